// Round 8
// baseline (202.749 us; speedup 1.0000x reference)
//
#include <hip/hip_runtime.h>

// B=2, S=2048, D=1024, H=16, hd=64, SCALE=32.
// softmax over batch axis (B=2) == pointwise sigmoid((s1-s0)/32); no k-normalization.
// Sigmoid scale log2(e)/32 is folded into Q at the QKV-GEMM epilogue.
// NOTE: p1 must be 1-p0 (NOT p0*e): e=exp2(dS) overflows to inf -> 0*inf=NaN.
//
// R13: R12 counters: no pipe >33%, ~3.3k cyc/tile overhead x16 barriers ->
// 64-key tiles (8 barriers), 2 buffers (64 KB LDS), 1-deep prefetch with
// vmcnt(0)-at-barrier (loads get a whole tile to land). Tile body = two 32-key
// halves with no barrier between -> half-B QK MFMAs overlap half-A sigmoid/PV
// VALU. QK K-fragment read once per s2, shared by both g chains (QK LDS reads
// halve). V rows now 64-wide: chunk swizzle ^= hd&7 (2-way max, free).

typedef _Float16 f16;
typedef __attribute__((ext_vector_type(8))) _Float16 f16x8;
typedef __attribute__((ext_vector_type(4))) _Float16 f16x4;
typedef __attribute__((ext_vector_type(4))) float f32x4;
typedef __attribute__((ext_vector_type(16))) float f32x16;

#define MFMA16(a,b,c)  __builtin_amdgcn_mfma_f32_16x16x32_f16(a,b,c,0,0,0)
#define MFMA32(a,b,c)  __builtin_amdgcn_mfma_f32_32x32x16_f16(a,b,c,0,0,0)
#define GLD16(gp, lp) __builtin_amdgcn_global_load_lds(                         \
    (const __attribute__((address_space(1))) void*)(gp),                        \
    (__attribute__((address_space(3))) void*)(lp), 16, 0, 0)

// ---------------- fused prep: w transposes (blocks 0..1023) + x convert (1024..5119) ----------------
__global__ __launch_bounds__(256) void prep(const float* __restrict__ x,
                                            const float* __restrict__ w0, const float* __restrict__ w1,
                                            const float* __restrict__ w2, const float* __restrict__ w3,
                                            f16* __restrict__ xh,
                                            f16* __restrict__ o0, f16* __restrict__ o1,
                                            f16* __restrict__ o2, f16* __restrict__ o3) {
    const int bb = blockIdx.x;
    const int tid = threadIdx.x;
    if (bb >= 1024) {
        int i = (bb - 1024) * 256 + tid;
        float4 v = ((const float4*)x)[i];
        f16x4 h;
        h[0] = (f16)v.x; h[1] = (f16)v.y; h[2] = (f16)v.z; h[3] = (f16)v.w;
        *(f16x4*)(xh + (long)i * 4) = h;
        return;
    }
    const float* w; f16* o;
    switch (bb & 3) {
        case 0: w = w0; o = o0; break;
        case 1: w = w1; o = o1; break;
        case 2: w = w2; o = o2; break;
        default: w = w3; o = o3; break;
    }
    __shared__ alignas(16) f16 t[64][72];
    const int d0 = ((bb >> 2) & 15) * 64, j0 = (bb >> 6) * 64;
    #pragma unroll
    for (int it = 0; it < 4; ++it) {
        int idx = it * 256 + tid;
        int row = idx >> 4, c4 = idx & 15;
        float4 v = *(const float4*)(w + (long)(d0 + row) * 1024 + j0 + c4 * 4);
        f16x4 h;
        h[0] = (f16)v.x; h[1] = (f16)v.y; h[2] = (f16)v.z; h[3] = (f16)v.w;
        *(f16x4*)&t[row][c4 * 4] = h;
    }
    __syncthreads();
    #pragma unroll
    for (int it = 0; it < 4; ++it) {
        int idx = it * 256 + tid;
        int jr = idx >> 4, d4 = idx & 15;
        f16x4 h;
        #pragma unroll
        for (int m = 0; m < 4; ++m) h[m] = t[d4 * 4 + m][jr];
        *(f16x4*)(o + (long)(j0 + jr) * 1024 + d0 + d4 * 4) = h;
    }
}

// ---------------- fused QKV GEMM: [4096x1024] @ Wt^T, Wt = [wqT;wkT;wvT] [3072][1024] ----------------
// Epilogue: Q/K written into batch-concat layouts Qc/Kc [16][2048][128]:
// d 0..63 = batch1, d 64..127 = batch0; K batch0 negated; Q scaled by log2(e)/32.
__global__ __launch_bounds__(256, 1) void gemm_qkv(const f16* __restrict__ A,
                                                   const f16* __restrict__ Wt,
                                                   f16* __restrict__ Qc,
                                                   f16* __restrict__ Kc,
                                                   f16* __restrict__ Vtg) {
    __shared__ alignas(16) f16 smem[16384];          // As = [0:8192) 128x64, Bs = [8192:) 128x64
    f16* As = smem;
    f16* Bs = smem + 8192;
    const int tid = threadIdx.x;
    const int wave = tid >> 6, lane = tid & 63;
    const int l15 = lane & 15, lq = lane >> 4;
    const int sw = l15 & 7;
    const int m0 = blockIdx.x * 128, n0 = blockIdx.y * 128;
    const int wr = (wave >> 1) * 64, wc = (wave & 1) * 64;
    const int r8 = lane >> 3;
    const int swc8 = ((lane & 7) ^ r8) * 8;

    f32x4 acc[4][4] = {};

    for (int kt = 0; kt < 16; ++kt) {       // K = 1024, BK = 64
        __syncthreads();
        #pragma unroll
        for (int i = 0; i < 4; ++i) {
            GLD16(A  + (long)(m0 + wave * 32 + i * 8 + r8) * 1024 + kt * 64 + swc8, As + (wave * 32 + i * 8) * 64);
            GLD16(Wt + (long)(n0 + wave * 32 + i * 8 + r8) * 1024 + kt * 64 + swc8, Bs + (wave * 32 + i * 8) * 64);
        }
        __syncthreads();
        #pragma unroll
        for (int s2 = 0; s2 < 2; ++s2) {
            const int rc = ((s2 * 4 + lq) ^ sw) << 3;
            f16x8 af[4], bf[4];
            #pragma unroll
            for (int i = 0; i < 4; ++i) af[i] = *(const f16x8*)&As[(wr + i * 16 + l15) * 64 + rc];
            #pragma unroll
            for (int j = 0; j < 4; ++j) bf[j] = *(const f16x8*)&Bs[(wc + j * 16 + l15) * 64 + rc];
            #pragma unroll
            for (int i = 0; i < 4; ++i)
                #pragma unroll
                for (int j = 0; j < 4; ++j)
                    acc[i][j] = MFMA16(af[i], bf[j], acc[i][j]);
        }
    }

    const int sel = n0 >> 10;                       // 0:Q 1:K 2:V (block-uniform)
    const int nb = n0 - (sel << 10);

    if (sel < 2) {
        f16* dst = sel == 0 ? Qc : Kc;
        const int b = m0 >> 11;                            // block-uniform batch
        const int boff = b ? 0 : 64;                       // batch1 -> d 0..63, batch0 -> 64..127
        const float qs = sel == 0 ? 0.045084219f           // log2(e)/32
                                  : (b == 0 ? -1.0f : 1.0f);  // negate K batch0
        __syncthreads();
        #pragma unroll
        for (int i = 0; i < 4; ++i)
            #pragma unroll
            for (int j = 0; j < 4; ++j) {
                int row0 = wr + i * 16 + lq * 4;
                int colb = wc + j * 16 + l15;
                int chunk = colb >> 3, sub = colb & 7;
                #pragma unroll
                for (int r = 0; r < 4; ++r) {
                    int row = row0 + r;
                    smem[row * 128 + ((chunk ^ (row & 7)) << 3) + sub] = (f16)(acc[i][j][r] * qs);
                }
            }
        __syncthreads();
        #pragma unroll
        for (int e = 0; e < 8; ++e) {
            int id = e * 256 + tid;
            int row = id >> 4, c = id & 15;
            f16x8 v = *(const f16x8*)&smem[row * 128 + ((c ^ (row & 7)) << 3)];
            int gr = m0 + row, s = gr & 2047;
            int gc = nb + c * 8, hh = gc >> 6, hd = gc & 63;
            *(f16x8*)(dst + (long)(hh * 2048 + s) * 128 + boff + hd) = v;
        }
    } else {
        #pragma unroll
        for (int i = 0; i < 4; ++i)
            #pragma unroll
            for (int j = 0; j < 4; ++j) {
                int gr0 = m0 + wr + i * 16 + lq * 4;
                int gc  = nb + wc + j * 16 + l15;
                int b = gr0 >> 11, s = gr0 & 2047;
                int hh = gc >> 6, hd = gc & 63;
                f16x4 v;
                #pragma unroll
                for (int r = 0; r < 4; ++r) v[r] = (f16)acc[i][j][r];
                *(f16x4*)(Vtg + (long)((b * 16 + hh) * 64 + hd) * 2048 + s) = v;
            }
    }
}

// ---------------- output GEMM: fp32 out = (vals0+..+valsN) @ woT^T ----------------
template<int NSUM>
__global__ __launch_bounds__(256, 1) void gemm_out(const f16* __restrict__ A0,
                                                   const f16* __restrict__ A1,
                                                   const f16* __restrict__ A2,
                                                   const f16* __restrict__ A3,
                                                   const f16* __restrict__ Bt,
                                                   float* __restrict__ outp) {
    __shared__ alignas(16) f16 As[64][72];
    __shared__ alignas(16) f16 Bs[128][64];
    const int tid = threadIdx.x;
    const int wave = tid >> 6, lane = tid & 63;
    const int l15 = lane & 15, lq = lane >> 4;
    const int sw = l15 & 7;
    const int m0 = blockIdx.x * 64, n0 = blockIdx.y * 128;
    const int wr = (wave >> 1) * 32, wc = (wave & 1) * 64;
    const int r8 = lane >> 3;
    const int swc8 = ((lane & 7) ^ r8) * 8;

    f32x4 acc[2][4] = {};

    for (int kt = 0; kt < 16; ++kt) {
        __syncthreads();
        #pragma unroll
        for (int it = 0; it < 2; ++it) {
            int idx = it * 256 + tid;
            int row = idx >> 3, c = idx & 7;
            long off = (long)(m0 + row) * 1024 + kt * 64 + c * 8;
            f16x8 a = *(const f16x8*)(A0 + off) + *(const f16x8*)(A1 + off);
            if constexpr (NSUM >= 3) a = a + *(const f16x8*)(A2 + off);
            if constexpr (NSUM >= 4) a = a + *(const f16x8*)(A3 + off);
            *(f16x8*)&As[row][c * 8] = a;
        }
        #pragma unroll
        for (int i = 0; i < 4; ++i)
            GLD16(Bt + (long)(n0 + wave * 32 + i * 8 + r8) * 1024 + kt * 64 + swc8, &Bs[wave * 32 + i * 8][0]);
        __syncthreads();
        #pragma unroll
        for (int s2 = 0; s2 < 2; ++s2) {
            const int rc = ((s2 * 4 + lq) ^ sw) << 3;
            f16x8 af[2], bf[4];
            #pragma unroll
            for (int i = 0; i < 2; ++i) af[i] = *(const f16x8*)&As[wr + i * 16 + l15][s2 * 32 + lq * 8];
            #pragma unroll
            for (int j = 0; j < 4; ++j) bf[j] = *(const f16x8*)&Bs[wc + j * 16 + l15][rc];
            #pragma unroll
            for (int i = 0; i < 2; ++i)
                #pragma unroll
                for (int j = 0; j < 4; ++j)
                    acc[i][j] = MFMA16(af[i], bf[j], acc[i][j]);
        }
    }

    #pragma unroll
    for (int i = 0; i < 2; ++i)
        #pragma unroll
        for (int j = 0; j < 4; ++j) {
            int gr0 = m0 + wr + i * 16 + lq * 4;
            int gc  = n0 + wc + j * 16 + l15;
            #pragma unroll
            for (int r = 0; r < 4; ++r)
                outp[(long)(gr0 + r) * 1024 + gc] = acc[i][j][r];
        }
}

// ---------------- fused batch-coupled attention: q=64/wave, concat-K dS, 64-key tiles ----------------
// 2 LDS buffers (64 KB), 1-deep prefetch, vmcnt(0)+s_barrier per 64-key tile (8 iters).
// grid 512 (16h x 8qt x 4ks) = 2 blocks/CU. Tile body = two 32-key halves, no barrier
// between (half-B QK overlaps half-A sigmoid/PV). K-fragment shared across both g.
__global__ __launch_bounds__(256, 2) void attention_kernel(const f16* __restrict__ Qc,
                                                           const f16* __restrict__ Kc,
                                                           const f16* __restrict__ Vtg,
                                                           f16* __restrict__ v0,
                                                           f16* __restrict__ v1,
                                                           f16* __restrict__ v2,
                                                           f16* __restrict__ v3) {
    __shared__ alignas(16) f16 KsC[2][64][128];      // [buf][key][dc]            32 KB
    __shared__ alignas(16) f16 Vts[2][2][64][64];    // [buf][batch][hd][key-swz] 32 KB
    const int tid = threadIdx.x;
    const int wave = tid >> 6, lane = tid & 63;
    const int l31 = lane & 31, hi = lane >> 5;
    const int kch = l31 & 15;          // K-row (256B) chunk swizzle = row&15
    const int vch = l31 & 7;           // V-row (128B) chunk swizzle = row&7

    const int bid = blockIdx.x;
    const int xcd = bid & 7, sl = bid >> 3;
    const int h  = xcd * 2 + (sl & 1);               // head pinned to XCD
    const int qt = (sl >> 1) & 7, ks = sl >> 4;
    const int q0 = qt * 256;
    const int key0 = ks * 512;                       // 8 tiles of 64 keys per split
    const int nt = 8;
    f16* vals = ks == 0 ? v0 : ks == 1 ? v1 : ks == 2 ? v2 : v3;
    const int qr = q0 + wave * 64;

    // Qc fragments (B-operand): [g][s2], d-chunk = s2*16 + hi*8, col q = qr + g*32 + l31
    f16x8 qfr[2][8];
    #pragma unroll
    for (int g = 0; g < 2; ++g)
        #pragma unroll
        for (int s2 = 0; s2 < 8; ++s2)
            qfr[g][s2] = *(const f16x8*)(Qc + (long)(h * 2048 + qr + g * 32 + l31) * 128
                                         + s2 * 16 + hi * 8);

    f32x16 acc[2][2][2] = {};                        // [pb][g][hdh]; D[row=hd][col=q]

    // K staging (waves 0,1): kw covers rows kw*32 + i*4 + (lane>>4), i=0..7.
    // Phys chunk lane&15 holds logical chunk (lane&15) ^ (row&15).
    const int kw = wave & 1;
    const f16* kbase = Kc + (long)(h * 2048 + key0 + kw * 32 + (lane >> 4)) * 128;
    // V staging (waves 2,3): batch tb; hd = i*8 + (lane>>3); phys chunk lane&7 holds
    // logical (lane&7) ^ ((lane>>3)&7).
    const int tb = wave & 1;
    const f16* vbase = Vtg + (long)((tb * 16 + h) * 64 + (lane >> 3)) * 2048 + key0
                       + ((lane & 7) ^ ((lane >> 3) & 7)) * 8;

    auto stage = [&](int kt, int buf) {              // exactly 8 GLD16 per wave
        if (wave < 2) {
            f16* l = &KsC[buf][kw * 32][0];
            #pragma unroll
            for (int i = 0; i < 8; ++i) {
                const int gch = ((lane & 15) ^ (((i & 3) << 2) | (lane >> 4))) << 3;
                GLD16(kbase + (long)kt * 8192 + i * 512 + gch, l + i * 512);
            }
        } else {
            const f16* g = vbase + kt * 64;
            f16* l = &Vts[buf][tb][0][0];
            #pragma unroll
            for (int i = 0; i < 8; ++i) GLD16(g + (long)i * 8 * 2048, l + i * 512);
        }
    };

    const f16x8 ones8 = {(f16)1.f,(f16)1.f,(f16)1.f,(f16)1.f,(f16)1.f,(f16)1.f,(f16)1.f,(f16)1.f};

    stage(0, 0);
    for (int kt = 0; kt < nt; ++kt) {
        const int cur = kt & 1;
        // stage(kt) was issued one full tile ago -> this wait is ~free
        asm volatile("s_waitcnt vmcnt(0)" ::: "memory");
        __builtin_amdgcn_s_barrier();
        __builtin_amdgcn_sched_barrier(0);
        if (kt + 1 < nt) stage(kt + 1, cur ^ 1);     // WAR-safe: buf^1 readers done pre-barrier

        #pragma unroll
        for (int hkey = 0; hkey < 2; ++hkey) {       // two 32-key halves, no barrier between
            // ---- dS = [K1|-K0]·[Q1|Q0]: one K-read feeds both g chains ----
            f32x16 S0 = {}, S1 = {};
            __builtin_amdgcn_s_setprio(1);
            #pragma unroll
            for (int s2 = 0; s2 < 8; ++s2) {
                f16x8 a = *(const f16x8*)&KsC[cur][hkey * 32 + l31][(((s2 * 2 + hi) ^ kch) << 3)];
                S0 = MFMA32(a, qfr[0][s2], S0);
                S1 = MFMA32(a, qfr[1][s2], S1);
            }
            __builtin_amdgcn_s_setprio(0);

            // ---- sigmoid + pack + permlane -> PV B-fragments ----
            f16x8 pf0[2][2];                         // [g][keyh]
            #pragma unroll
            for (int g = 0; g < 2; ++g) {
                const f32x16& S = g ? S1 : S0;
                unsigned pk[8];
                #pragma unroll
                for (int p = 0; p < 8; ++p) {
                    float e0 = __builtin_amdgcn_exp2f(S[2 * p]);
                    float e1 = __builtin_amdgcn_exp2f(S[2 * p + 1]);
                    float pa = __builtin_amdgcn_rcpf(1.0f + e0);   // e=inf -> p=0 (safe)
                    float pb = __builtin_amdgcn_rcpf(1.0f + e1);
                    auto h2 = __builtin_amdgcn_cvt_pkrtz(pa, pb);
                    pk[p] = __builtin_bit_cast(unsigned, h2);
                }
                #pragma unroll
                for (int keyh = 0; keyh < 2; ++keyh) {
                    unsigned a0 = pk[4 * keyh + 0], b0 = pk[4 * keyh + 2];
                    unsigned a1 = pk[4 * keyh + 1], b1 = pk[4 * keyh + 3];
                    asm("v_permlane32_swap_b32 %0, %1" : "+v"(a0), "+v"(b0));
                    asm("v_permlane32_swap_b32 %0, %1" : "+v"(a1), "+v"(b1));
                    union { unsigned u[4]; f16x8 v; } m;
                    m.u[0] = a0; m.u[1] = a1; m.u[2] = b0; m.u[3] = b1;
                    pf0[g][keyh] = m.v;
                }
            }

            // ---- PV: O^T[hd][q] += V^T[hd][key] * P^T[key][q]; V frags shared across g ----
            __builtin_amdgcn_s_setprio(1);
            #pragma unroll
            for (int pb = 0; pb < 2; ++pb)
                #pragma unroll
                for (int keyh = 0; keyh < 2; ++keyh) {
                    f16x8 vf[2];
                    #pragma unroll
                    for (int hdh = 0; hdh < 2; ++hdh)
                        vf[hdh] = *(const f16x8*)&Vts[cur][pb][hdh * 32 + l31]
                                      [(((hkey * 4 + keyh * 2 + hi) ^ vch) << 3)];
                    #pragma unroll
                    for (int g = 0; g < 2; ++g) {
                        const f16x8 pfr = pb ? (ones8 - pf0[g][keyh]) : pf0[g][keyh];
                        #pragma unroll
                        for (int hdh = 0; hdh < 2; ++hdh)
                            acc[pb][g][hdh] = MFMA32(vf[hdh], pfr, acc[pb][g][hdh]);
                    }
                }
            __builtin_amdgcn_s_setprio(0);
        }
    }

    // D[row=hd=hdh*32+gg*8+hi*4+r2][col=q=qr+g*32+l31] -> f16x4 stores along hd
    #pragma unroll
    for (int pb = 0; pb < 2; ++pb)
        #pragma unroll
        for (int g = 0; g < 2; ++g)
            #pragma unroll
            for (int hdh = 0; hdh < 2; ++hdh)
                #pragma unroll
                for (int gg = 0; gg < 4; ++gg) {
                    f16x4 ov;
                    #pragma unroll
                    for (int r2 = 0; r2 < 4; ++r2) ov[r2] = (f16)acc[pb][g][hdh][gg * 4 + r2];
                    *(f16x4*)(vals + (long)(pb * 2048 + qr + g * 32 + l31) * 1024
                              + h * 64 + hdh * 32 + gg * 8 + hi * 4) = ov;
                }
}

extern "C" void kernel_launch(void* const* d_in, const int* in_sizes, int n_in,
                              void* d_out, int out_size, void* d_ws, size_t ws_size,
                              hipStream_t stream) {
    const float* x  = (const float*)d_in[0];
    const float* wq = (const float*)d_in[1];
    const float* wk = (const float*)d_in[2];
    const float* wv = (const float*)d_in[3];
    const float* wo = (const float*)d_in[4];

    char* ws = (char*)d_ws;
    f16* xh    = (f16*)(ws);                   // 8 MiB; dead after QKV gemm -> reused as vals0
    f16* wqT   = (f16*)(ws + 8388608);         // wqT,wkT,wvT contiguous = fused [3072][1024]
    f16* wkT   = (f16*)(ws + 10485760);
    f16* wvT   = (f16*)(ws + 12582912);
    f16* woT   = (f16*)(ws + 14680064);
    f16* Qc    = (f16*)(ws + 16777216);        // [16][2048][128] concat: d<64=b1, d>=64=b0
    f16* Kc    = (f16*)(ws + 25165824);        // [16][2048][128] concat: [K1 | -K0]
    f16* Vtg   = (f16*)(ws + 33554432);        // [2][16][64][2048]
    f16* vals1 = (f16*)(ws + 41943040);
    f16* vals2 = (f16*)(ws + 50331648);
    f16* vals3 = (f16*)(ws + 58720256);
    f16* vals0 = xh;
    (void)in_sizes; (void)n_in; (void)out_size; (void)ws_size;

    prep<<<5120, 256, 0, stream>>>(x, wq, wk, wv, wo, xh, wqT, wkT, wvT, woT);

    gemm_qkv<<<dim3(32, 24), 256, 0, stream>>>(xh, wqT, Qc, Kc, Vtg);

    attention_kernel<<<512, 256, 0, stream>>>(Qc, Kc, Vtg, vals0, vals1, vals2, vals3);

    gemm_out<4><<<dim3(64, 8), 256, 0, stream>>>(vals0, vals1, vals2, vals3, woT, (float*)d_out);
}